// Round 21
// baseline (446.265 us; speedup 1.0000x reference)
//
#include <hip/hip_runtime.h>
#include <math.h>

using short8 = __attribute__((ext_vector_type(8))) short;
using f32x16 = __attribute__((ext_vector_type(16))) float;

// ---------------- workspace byte offsets ----------------
// A2: conv1 out, frag-ordered [qyqx 361][cis 16][b 256][ci16 16] bf16 hi/lo
static const size_t B_QHI = 0;
static const size_t B_QLO = 47316992;
// B2: w2 frag-ordered [k 81][cg 8][cis 16][c 32][ci16 16] bf16 hi/lo
static const size_t B_WHI = 94633984;
static const size_t B_WLO = 105250816;
// h2t kh=0 partial (fp32 [c*36+p][b]) and kh=1 partial
static const size_t B_H2  = 115867648;          // ends 125,304,832
static const size_t B_H2B = 125304832;          // ends 134,742,016
static const size_t B_END_SPLIT = 134742016;
// post-conv2 aliases (A2/B2 dead after conv2):
static const size_t B_UH  = 0;                  // uhat bf16 [160][1152][256], 94,371,840
static const size_t B_OB  = 94633984;           // ob fp32 [160][256], ends 94,797,824
static const size_t B_CP  = 94797824;           // colpart fp32 [128][160][256] = 20,971,520
                                                // ends 115,769,344 <= B_H2 (h2t intact)

__device__ __forceinline__ unsigned short bf16_rne(float v) {
    unsigned int u = __builtin_bit_cast(unsigned int, v);
    u += 0x7FFFu + ((u >> 16) & 1u);
    return (unsigned short)(u >> 16);
}
__device__ __forceinline__ float bf16_tof(unsigned short h) {
    unsigned int u = ((unsigned int)h) << 16;
    return __builtin_bit_cast(float, u);
}

// ---------------- prep: conv1 (blocks 0..511) + w2t (512..1023) -------------
__global__ __launch_bounds__(256) void prep_kernel(
        const float* __restrict__ x, const float* __restrict__ w1,
        const float* __restrict__ b1, const float* __restrict__ w2,
        unsigned short* __restrict__ qhi, unsigned short* __restrict__ qlo,
        unsigned short* __restrict__ whi, unsigned short* __restrict__ wlo) {
    __shared__ float sh[10368];          // union: conv1 xs (560 f) / w2t buf (10368 f)
    int blk = blockIdx.x;
    int t = threadIdx.x;
    if (blk < 512) {
        // ---- conv1: b = blk>>1, xh = blk&1 ----
        int b = blk >> 1, xh = blk & 1, c = t;
        float (*xs)[20] = (float(*)[20])sh;
        for (int i = c; i < 560; i += 256) {
            int row = i / 20, cl = i - row * 20, gc = xh * 10 + cl;
            xs[row][cl] = (gc < 28) ? x[(size_t)b*784 + row*28 + gc] : 0.f;
        }
        float wr[81];
        #pragma unroll
        for (int k = 0; k < 81; ++k) wr[k] = w1[c*81 + k];
        float bias = b1[c];
        __syncthreads();
        for (int oy = 0; oy < 19; ++oy) {
            float acc[12];
            #pragma unroll
            for (int e = 0; e < 12; ++e) acc[e] = 0.f;
            #pragma unroll
            for (int ky = 0; ky < 9; ++ky) {
                float xr[20];
                #pragma unroll
                for (int i = 0; i < 20; ++i) xr[i] = xs[oy + ky][i];
                #pragma unroll
                for (int kx = 0; kx < 9; ++kx) {
                    float wv_ = wr[ky*9 + kx];
                    #pragma unroll
                    for (int e = 0; e < 12; ++e)
                        acc[e] = fmaf(xr[e + kx], wv_, acc[e]);
                }
            }
            #pragma unroll
            for (int e = 0; e < 12; ++e) {
                int ox = xh*10 + e;
                if (e < 10 && ox < 19) {
                    float v = fmaxf(bias + acc[e], 0.f);
                    unsigned short hi = bf16_rne(v);
                    unsigned short lo = bf16_rne(v - bf16_tof(hi));
                    size_t o = ((size_t)((oy*19 + ox)*16 + (c >> 4))*256 + b)*16 + (c & 15);
                    qhi[o] = hi; qlo[o] = lo;
                }
            }
        }
    } else {
        // ---- w2t: idx = blk-512; c = idx>>1, half = idx&1 ----
        int idx = blk - 512;
        int c = idx >> 1, half = idx & 1;
        float* buf = sh;
        const float* src = w2 + (size_t)c*20736 + (size_t)half*128*81;
        for (int i = t; i < 128*81; i += 256) buf[i] = src[i];
        __syncthreads();
        int kk = t >> 7, cil = t & 127;
        int ci = half*128 + cil;
        size_t cbase = ((size_t)(c >> 5)*16 + (ci >> 4))*32 + (c & 31);
        for (int k2 = 0; k2 < 41; ++k2) {
            int k = k2*2 + kk;
            if (k < 81) {
                float v = buf[cil*81 + k];
                unsigned short hi = bf16_rne(v);
                unsigned short lo = bf16_rne(v - bf16_tof(hi));
                size_t o = (((size_t)k*4096 + cbase)*16) + (ci & 15);
                whi[o] = hi; wlo[o] = lo;
            }
        }
    }
}

// ---------------- conv2: full-row ox merge + kh split, LDS-free (R18) -------
__global__ __launch_bounds__(512) void conv2_mfma(
        const unsigned short* __restrict__ qhi, const unsigned short* __restrict__ qlo,
        const unsigned short* __restrict__ whi, const unsigned short* __restrict__ wlo,
        const float* __restrict__ b2, float* __restrict__ h2t) {
    int blk = blockIdx.x;               // 768 blocks
    int bt  = blk & 7;                  // low bits -> XCD partition by batch
    int rest = blk >> 3;
    int kh = rest & 1;  rest >>= 1;
    int cg = rest & 7;
    int oy = rest >> 3;                 // 0..5
    int t = threadIdx.x;
    int wv = t >> 6, l = t & 63;        // 8 waves
    int cis = kh*8 + wv;                // this wave's cis

    int loff = (l & 31)*16 + (l >> 5)*8;

    f32x16 acc[6];
    #pragma unroll
    for (int i = 0; i < 6; ++i)
        #pragma unroll
        for (int r = 0; r < 16; ++r) acc[i][r] = 0.f;

    #pragma unroll 1
    for (int ky = 0; ky < 9; ++ky) {
        int qy = oy*2 + ky;
        short8 afh[19], afl[19], bfh[9], bfl[9];
        size_t abase = (((size_t)(qy*19)*16 + cis)*256)*16 + (size_t)bt*512 + loff;
        #pragma unroll
        for (int q = 0; q < 19; ++q) {
            afh[q] = *(const short8*)(qhi + abase + (size_t)q*65536);
            afl[q] = *(const short8*)(qlo + abase + (size_t)q*65536);
        }
        size_t bbase = (((size_t)(ky*9)*8 + cg)*16 + cis)*512 + loff;
        #pragma unroll
        for (int kx = 0; kx < 9; ++kx) {
            bfh[kx] = *(const short8*)(whi + bbase + (size_t)kx*65536);
            bfl[kx] = *(const short8*)(wlo + bbase + (size_t)kx*65536);
        }
        #pragma unroll
        for (int kx = 0; kx < 9; ++kx) {
            #pragma unroll
            for (int oxl = 0; oxl < 6; ++oxl) {
                int q = 2*oxl + kx;
                acc[oxl] = __builtin_amdgcn_mfma_f32_32x32x16_bf16(afh[q], bfh[kx], acc[oxl], 0, 0, 0);
                acc[oxl] = __builtin_amdgcn_mfma_f32_32x32x16_bf16(afh[q], bfl[kx], acc[oxl], 0, 0, 0);
                acc[oxl] = __builtin_amdgcn_mfma_f32_32x32x16_bf16(afl[q], bfh[kx], acc[oxl], 0, 0, 0);
            }
        }
    }

    float* hp = h2t + (size_t)kh * 2359296;
    __shared__ float buf[4][3][16][64];    // 49,152 B (reused twice)
    #define REDUCE_STORE(A0, POFF)                                              \
    {                                                                           \
        if (wv < 4) {                                                           \
            _Pragma("unroll")                                                   \
            for (int i = 0; i < 3; ++i)                                         \
                _Pragma("unroll")                                               \
                for (int r = 0; r < 16; ++r) buf[wv][i][r][l] = acc[(A0)+i][r]; \
        }                                                                       \
        __syncthreads();                                                        \
        if (wv >= 4) {                                                          \
            _Pragma("unroll")                                                   \
            for (int i = 0; i < 3; ++i)                                         \
                _Pragma("unroll")                                               \
                for (int r = 0; r < 16; ++r) buf[wv-4][i][r][l] += acc[(A0)+i][r]; \
        }                                                                       \
        __syncthreads();                                                        \
        float* ebuf = &buf[0][0][0][0];                                         \
        if (wv == 0) {                                                          \
            float bv = (kh == 0) ? b2[cg*32 + (l & 31)] : 0.f;                  \
            float vals[3][16];                                                  \
            _Pragma("unroll")                                                   \
            for (int i = 0; i < 3; ++i)                                         \
                _Pragma("unroll")                                               \
                for (int r = 0; r < 16; ++r)                                    \
                    vals[i][r] = buf[0][i][r][l] + buf[1][i][r][l]              \
                               + buf[2][i][r][l] + buf[3][i][r][l] + bv;        \
            _Pragma("unroll")                                                   \
            for (int i = 0; i < 3; ++i)                                         \
                _Pragma("unroll")                                               \
                for (int r = 0; r < 16; ++r) {                                  \
                    int row = (r & 3) + 8*(r >> 2) + 4*(l >> 5);                \
                    ebuf[i*1056 + row*33 + (l & 31)] = vals[i][r];              \
                }                                                               \
        }                                                                       \
        __syncthreads();                                                        \
        _Pragma("unroll 1")                                                     \
        for (int pass = 0; pass < 6; ++pass) {                                  \
            int row_id = pass*16 + (t >> 5);                                    \
            int oxl = row_id >> 5, c = row_id & 31;                             \
            float v = ebuf[oxl*1056 + (t & 31)*33 + c];                         \
            int p = oy*6 + (POFF) + oxl;                                        \
            hp[(size_t)((cg*32 + c)*36 + p)*256 + bt*32 + (t & 31)] = v;        \
        }                                                                       \
        __syncthreads();                                                        \
    }
    REDUCE_STORE(0, 0)
    REDUCE_STORE(3, 3)
    #undef REDUCE_STORE
}

// -------- uhat: kh-partial sum + primary squash + u_hat + colpart -----------
// 1280 blocks (9 n each) for higher CU coverage; colpart has 128 chunks.
__global__ __launch_bounds__(256) void uhat_kernel(
        const float* __restrict__ h2t, const float* __restrict__ h2t2,
        const float* __restrict__ W, unsigned short* __restrict__ uhat,
        float* __restrict__ colpart) {
    int ch = blockIdx.x;      // 0..127 (9 n each)
    int c  = blockIdx.y;      // 0..9
    int t  = threadIdx.x;     // b
    __shared__ float Wl[1152];            // [9n][16i][8j]
    const float* wsrc = W + ((size_t)c*1152 + ch*9)*128;
    for (int i = t; i < 1152; i += 256) Wl[i] = wsrc[i];
    __syncthreads();
    float cp[16];
    #pragma unroll
    for (int i = 0; i < 16; ++i) cp[i] = 0.f;
    #pragma unroll 1
    for (int nn = 0; nn < 9; ++nn) {
        int n = ch*9 + nn;
        float v[8]; float sq = 0.f;
        #pragma unroll
        for (int j = 0; j < 8; ++j) {
            size_t idx = (size_t)(n*8 + j)*256 + t;
            v[j] = h2t[idx] + h2t2[idx];
            sq = fmaf(v[j], v[j], sq);
        }
        float sc = sq / (1.0f + sq);      // primary squash: NO /sqrt
        #pragma unroll
        for (int j = 0; j < 8; ++j) v[j] *= sc;
        #pragma unroll
        for (int i = 0; i < 16; ++i) {
            float uh = 0.f;
            #pragma unroll
            for (int j = 0; j < 8; ++j)
                uh = fmaf(Wl[(nn*16 + i)*8 + j], v[j], uh);
            unsigned short ub = bf16_rne(uh);
            uhat[((size_t)(c*16 + i)*1152 + n)*256 + t] = ub;
            cp[i] += bf16_tof(ub);        // chunk column-sum (bf16-rounded vals)
        }
    }
    #pragma unroll
    for (int i = 0; i < 16; ++i)
        colpart[(size_t)ch*40960 + (size_t)(c*16 + i)*256 + t] = cp[i];
}

// -------- rout: 3 routing iterations; 1024 thr (16 waves) per (c,i) ---------
// s-phase: 32 n-groups x 32 b-octets; delta: 16 waves x (2n x 32 bo), 36 passes.
__global__ __launch_bounds__(1024) void rout_kernel(
        const unsigned short* __restrict__ uhat, const float* __restrict__ colpart,
        float* __restrict__ ob) {
    int ci = blockIdx.x;      // 0..159
    int t  = threadIdx.x;     // 0..1023
    int wv = t >> 6, l = t & 63;
    const unsigned short* U = uhat + (size_t)ci*1152*256;
    __shared__ float bsum[1152];
    __shared__ float p[1152];
    __shared__ float outb[256];
    __shared__ float sred[32][256];       // 32 KB
    __shared__ float red[16];
    for (int k = t; k < 1152; k += 1024) bsum[k] = 0.f;
    __syncthreads();

    #define DELTA_PASS                                                          \
    {                                                                           \
        int nl = l >> 5, bo = l & 31;                                           \
        _Pragma("unroll 6")                                                     \
        for (int pass = 0; pass < 36; ++pass) {                                 \
            int n = pass*32 + wv*2 + nl;                                        \
            short8 u8 = *(const short8*)(U + (size_t)n*256 + bo*8);             \
            float d = 0.f;                                                      \
            _Pragma("unroll")                                                   \
            for (int e = 0; e < 8; ++e)                                         \
                d = fmaf(bf16_tof((unsigned short)u8[e]), outb[bo*8 + e], d);   \
            _Pragma("unroll")                                                   \
            for (int mm = 1; mm < 32; mm <<= 1) d += __shfl_xor(d, mm, 64);     \
            if (bo == 0) bsum[n] += d;                                          \
        }                                                                       \
    }

    // ---------------- iter 0: p uniform -> s from colpart ------------------
    {
        float s = 0.f;
        if (t < 256) {
            const float* cp = colpart + (size_t)ci*256 + t;
            #pragma unroll 8
            for (int ch = 0; ch < 128; ++ch) s += cp[(size_t)ch*40960];
            s *= (1.0f / 1152.0f);
        }
        float v2 = s * s;
        #pragma unroll
        for (int mm = 1; mm < 64; mm <<= 1) v2 += __shfl_xor(v2, mm, 64);
        if (t < 256 && l == 0) red[wv] = v2;   // waves 0..3
        __syncthreads();
        float total = red[0] + red[1] + red[2] + red[3];
        if (t < 256) {
            float scq = total / ((1.0f + total) * sqrtf(total));
            outb[t] = scq * s;
        }
        __syncthreads();
        DELTA_PASS
        __syncthreads();
    }

    // ---------------- iters 1,2 --------------------------------------------
    #pragma unroll 1
    for (int it = 1; it < 3; ++it) {
        // ---- softmax over n (1024 threads, 2 slices) ----
        float lv[2];
        float m = -1e30f;
        #pragma unroll
        for (int k = 0; k < 2; ++k) {
            int n = t + k*1024;
            lv[k] = (n < 1152) ? bsum[n] : -1e30f;
            m = fmaxf(m, lv[k]);
        }
        #pragma unroll
        for (int mm = 1; mm < 64; mm <<= 1) m = fmaxf(m, __shfl_xor(m, mm, 64));
        if (l == 0) red[wv] = m;
        __syncthreads();
        m = red[0];
        #pragma unroll
        for (int k = 1; k < 16; ++k) m = fmaxf(m, red[k]);
        __syncthreads();                   // WAR: red reused for sum
        float se = 0.f;
        #pragma unroll
        for (int k = 0; k < 2; ++k) {
            int n = t + k*1024;
            if (n < 1152) {
                float e = expf(lv[k] - m);
                p[n] = e;
                se += e;
            }
        }
        #pragma unroll
        for (int mm = 1; mm < 64; mm <<= 1) se += __shfl_xor(se, mm, 64);
        if (l == 0) red[wv] = se;
        __syncthreads();
        se = red[0];
        #pragma unroll
        for (int k = 1; k < 16; ++k) se += red[k];
        float inv = 1.0f / se;
        #pragma unroll
        for (int k = 0; k < 2; ++k) {
            int n = t + k*1024;
            if (n < 1152) p[n] *= inv;
        }
        __syncthreads();                   // p visible to all

        // ---- s-phase: thread (ng, bo) accumulates 8 b over its 36 n -------
        {
            int ng = t >> 5, bo = t & 31;
            float s8[8];
            #pragma unroll
            for (int e = 0; e < 8; ++e) s8[e] = 0.f;
            int n0 = ng * 36;
            #pragma unroll 6
            for (int nn = 0; nn < 36; ++nn) {
                int n = n0 + nn;
                float pv = p[n];
                short8 u8 = *(const short8*)(U + (size_t)n*256 + bo*8);
                #pragma unroll
                for (int e = 0; e < 8; ++e)
                    s8[e] = fmaf(pv, bf16_tof((unsigned short)u8[e]), s8[e]);
            }
            #pragma unroll
            for (int e = 0; e < 8; ++e) sred[ng][bo*8 + e] = s8[e];
        }
        __syncthreads();

        // ---- squash over b (threads 0..255) -------------------------------
        float s = 0.f;
        if (t < 256) {
            #pragma unroll
            for (int g = 0; g < 32; ++g) s += sred[g][t];
            float v2 = s * s;
            #pragma unroll
            for (int mm = 1; mm < 64; mm <<= 1) v2 += __shfl_xor(v2, mm, 64);
            if ((t & 63) == 0) red[t >> 6] = v2;
        }
        __syncthreads();
        float total = red[0] + red[1] + red[2] + red[3];
        if (t < 256) {
            float scq = total / ((1.0f + total) * sqrtf(total));
            float o = scq * s;
            if (it == 2) ob[(size_t)ci*256 + t] = o;
            else outb[t] = o;
        }
        if (it == 2) break;
        __syncthreads();                   // outb visible
        DELTA_PASS
        __syncthreads();
    }
    #undef DELTA_PASS
}

// -------- final: out[b,c] = sum_i outputs[c,i,b]^2 --------------------------
__global__ __launch_bounds__(256) void final_kernel(
        const float* __restrict__ obuf, float* __restrict__ out) {
    int c = blockIdx.x;
    int t = threadIdx.x;
    float s = 0.0f;
    #pragma unroll
    for (int i = 0; i < 16; ++i) {
        float v = obuf[((size_t)c*16 + i)*256 + t];
        s = fmaf(v, v, s);
    }
    out[(size_t)t*10 + c] = s;
}

// ---------------------------------------------------------------------------
extern "C" void kernel_launch(void* const* d_in, const int* in_sizes, int n_in,
                              void* d_out, int out_size, void* d_ws, size_t ws_size,
                              hipStream_t stream) {
    const float* x  = (const float*)d_in[0];
    const float* w1 = (const float*)d_in[1];
    const float* b1 = (const float*)d_in[2];
    const float* w2 = (const float*)d_in[3];
    const float* b2 = (const float*)d_in[4];
    const float* W  = (const float*)d_in[5];
    float* out = (float*)d_out;
    (void)in_sizes; (void)n_in; (void)out_size;

    if (ws_size < B_END_SPLIT) return;

    char* wsb = (char*)d_ws;
    unsigned short* qhi = (unsigned short*)(wsb + B_QHI);
    unsigned short* qlo = (unsigned short*)(wsb + B_QLO);
    unsigned short* whi = (unsigned short*)(wsb + B_WHI);
    unsigned short* wlo = (unsigned short*)(wsb + B_WLO);
    float* h2t  = (float*)(wsb + B_H2);
    float* h2t2 = (float*)(wsb + B_H2B);
    unsigned short* uh = (unsigned short*)(wsb + B_UH);   // aliases A2 (dead)
    float* ob = (float*)(wsb + B_OB);                     // aliases whi (dead)
    float* cp = (float*)(wsb + B_CP);                     // aliases whi/wlo (dead)

    prep_kernel<<<1024, 256, 0, stream>>>(x, w1, b1, w2, qhi, qlo, whi, wlo);
    conv2_mfma<<<768, 512, 0, stream>>>(qhi, qlo, whi, wlo, b2, h2t);
    uhat_kernel<<<dim3(128, 10), 256, 0, stream>>>(h2t, h2t2, W, uh, cp);
    rout_kernel<<<160, 1024, 0, stream>>>(uh, cp, ob);
    final_kernel<<<10, 256, 0, stream>>>(ob, out);
}

// Round 22
// 436.927 us; speedup vs baseline: 1.0214x; 1.0214x over previous
//
#include <hip/hip_runtime.h>
#include <math.h>

using short8 = __attribute__((ext_vector_type(8))) short;
using f32x16 = __attribute__((ext_vector_type(16))) float;

// ---------------- workspace byte offsets ----------------
// A2: conv1 out, frag-ordered [qyqx 361][cis 16][b 256][ci16 16] bf16 hi/lo
static const size_t B_QHI = 0;
static const size_t B_QLO = 47316992;
// B2: w2 frag-ordered [k 81][cg 8][cis 16][c 32][ci16 16] bf16 hi/lo
static const size_t B_WHI = 94633984;
static const size_t B_WLO = 105250816;
// h2t kh=0 partial (fp32 [c*36+p][b]) and kh=1 partial
static const size_t B_H2  = 115867648;          // ends 125,304,832
static const size_t B_H2B = 125304832;          // ends 134,742,016
static const size_t B_END_SPLIT = 134742016;
// post-conv2 aliases (A2/B2 dead after conv2):
static const size_t B_UH  = 0;                  // uhat bf16 [160][1152][256], 94,371,840
static const size_t B_OB  = 94633984;           // ob fp32 [160][256], ends 94,797,824
static const size_t B_CP  = 94797824;           // colpart fp32 [72][160][256], ends 106,594,304

__device__ __forceinline__ unsigned short bf16_rne(float v) {
    unsigned int u = __builtin_bit_cast(unsigned int, v);
    u += 0x7FFFu + ((u >> 16) & 1u);
    return (unsigned short)(u >> 16);
}
__device__ __forceinline__ float bf16_tof(unsigned short h) {
    unsigned int u = ((unsigned int)h) << 16;
    return __builtin_bit_cast(float, u);
}

// ---------------- prep: conv1 (blocks 0..511) + w2t (512..1023) -------------
__global__ __launch_bounds__(256) void prep_kernel(
        const float* __restrict__ x, const float* __restrict__ w1,
        const float* __restrict__ b1, const float* __restrict__ w2,
        unsigned short* __restrict__ qhi, unsigned short* __restrict__ qlo,
        unsigned short* __restrict__ whi, unsigned short* __restrict__ wlo) {
    __shared__ float sh[10368];          // union: conv1 xs (560 f) / w2t buf (10368 f)
    int blk = blockIdx.x;
    int t = threadIdx.x;
    if (blk < 512) {
        // ---- conv1: b = blk>>1, xh = blk&1 ----
        int b = blk >> 1, xh = blk & 1, c = t;
        float (*xs)[20] = (float(*)[20])sh;
        for (int i = c; i < 560; i += 256) {
            int row = i / 20, cl = i - row * 20, gc = xh * 10 + cl;
            xs[row][cl] = (gc < 28) ? x[(size_t)b*784 + row*28 + gc] : 0.f;
        }
        float wr[81];
        #pragma unroll
        for (int k = 0; k < 81; ++k) wr[k] = w1[c*81 + k];
        float bias = b1[c];
        __syncthreads();
        for (int oy = 0; oy < 19; ++oy) {
            float acc[12];
            #pragma unroll
            for (int e = 0; e < 12; ++e) acc[e] = 0.f;
            #pragma unroll
            for (int ky = 0; ky < 9; ++ky) {
                float xr[20];
                #pragma unroll
                for (int i = 0; i < 20; ++i) xr[i] = xs[oy + ky][i];
                #pragma unroll
                for (int kx = 0; kx < 9; ++kx) {
                    float wv_ = wr[ky*9 + kx];
                    #pragma unroll
                    for (int e = 0; e < 12; ++e)
                        acc[e] = fmaf(xr[e + kx], wv_, acc[e]);
                }
            }
            #pragma unroll
            for (int e = 0; e < 12; ++e) {
                int ox = xh*10 + e;
                if (e < 10 && ox < 19) {
                    float v = fmaxf(bias + acc[e], 0.f);
                    unsigned short hi = bf16_rne(v);
                    unsigned short lo = bf16_rne(v - bf16_tof(hi));
                    size_t o = ((size_t)((oy*19 + ox)*16 + (c >> 4))*256 + b)*16 + (c & 15);
                    qhi[o] = hi; qlo[o] = lo;
                }
            }
        }
    } else {
        // ---- w2t: idx = blk-512; c = idx>>1, half = idx&1 ----
        int idx = blk - 512;
        int c = idx >> 1, half = idx & 1;
        float* buf = sh;
        const float* src = w2 + (size_t)c*20736 + (size_t)half*128*81;
        for (int i = t; i < 128*81; i += 256) buf[i] = src[i];
        __syncthreads();
        int kk = t >> 7, cil = t & 127;
        int ci = half*128 + cil;
        size_t cbase = ((size_t)(c >> 5)*16 + (ci >> 4))*32 + (c & 31);
        for (int k2 = 0; k2 < 41; ++k2) {
            int k = k2*2 + kk;
            if (k < 81) {
                float v = buf[cil*81 + k];
                unsigned short hi = bf16_rne(v);
                unsigned short lo = bf16_rne(v - bf16_tof(hi));
                size_t o = (((size_t)k*4096 + cbase)*16) + (ci & 15);
                whi[o] = hi; wlo[o] = lo;
            }
        }
    }
}

// ---------------- conv2: full-row ox merge + kh split, LDS-free -------------
// B fragments issued BEFORE A: first MFMA (kx=0, needs bf[0]+af[0..]) can
// start while the 38-chunk A stream is still in flight.
__global__ __launch_bounds__(512) void conv2_mfma(
        const unsigned short* __restrict__ qhi, const unsigned short* __restrict__ qlo,
        const unsigned short* __restrict__ whi, const unsigned short* __restrict__ wlo,
        const float* __restrict__ b2, float* __restrict__ h2t) {
    int blk = blockIdx.x;               // 768 blocks
    int bt  = blk & 7;                  // low bits -> XCD partition by batch
    int rest = blk >> 3;
    int kh = rest & 1;  rest >>= 1;
    int cg = rest & 7;
    int oy = rest >> 3;                 // 0..5
    int t = threadIdx.x;
    int wv = t >> 6, l = t & 63;        // 8 waves
    int cis = kh*8 + wv;                // this wave's cis

    int loff = (l & 31)*16 + (l >> 5)*8;

    f32x16 acc[6];
    #pragma unroll
    for (int i = 0; i < 6; ++i)
        #pragma unroll
        for (int r = 0; r < 16; ++r) acc[i][r] = 0.f;

    #pragma unroll 1
    for (int ky = 0; ky < 9; ++ky) {
        int qy = oy*2 + ky;
        short8 afh[19], afl[19], bfh[9], bfl[9];
        size_t bbase = (((size_t)(ky*9)*8 + cg)*16 + cis)*512 + loff;
        #pragma unroll
        for (int kx = 0; kx < 9; ++kx) {
            bfh[kx] = *(const short8*)(whi + bbase + (size_t)kx*65536);
            bfl[kx] = *(const short8*)(wlo + bbase + (size_t)kx*65536);
        }
        size_t abase = (((size_t)(qy*19)*16 + cis)*256)*16 + (size_t)bt*512 + loff;
        #pragma unroll
        for (int q = 0; q < 19; ++q) {
            afh[q] = *(const short8*)(qhi + abase + (size_t)q*65536);
            afl[q] = *(const short8*)(qlo + abase + (size_t)q*65536);
        }
        #pragma unroll
        for (int kx = 0; kx < 9; ++kx) {
            #pragma unroll
            for (int oxl = 0; oxl < 6; ++oxl) {
                int q = 2*oxl + kx;
                acc[oxl] = __builtin_amdgcn_mfma_f32_32x32x16_bf16(afh[q], bfh[kx], acc[oxl], 0, 0, 0);
                acc[oxl] = __builtin_amdgcn_mfma_f32_32x32x16_bf16(afh[q], bfl[kx], acc[oxl], 0, 0, 0);
                acc[oxl] = __builtin_amdgcn_mfma_f32_32x32x16_bf16(afl[q], bfh[kx], acc[oxl], 0, 0, 0);
            }
        }
    }

    float* hp = h2t + (size_t)kh * 2359296;
    __shared__ float buf[4][3][16][64];    // 49,152 B (reused twice)
    #define REDUCE_STORE(A0, POFF)                                              \
    {                                                                           \
        if (wv < 4) {                                                           \
            _Pragma("unroll")                                                   \
            for (int i = 0; i < 3; ++i)                                         \
                _Pragma("unroll")                                               \
                for (int r = 0; r < 16; ++r) buf[wv][i][r][l] = acc[(A0)+i][r]; \
        }                                                                       \
        __syncthreads();                                                        \
        if (wv >= 4) {                                                          \
            _Pragma("unroll")                                                   \
            for (int i = 0; i < 3; ++i)                                         \
                _Pragma("unroll")                                               \
                for (int r = 0; r < 16; ++r) buf[wv-4][i][r][l] += acc[(A0)+i][r]; \
        }                                                                       \
        __syncthreads();                                                        \
        float* ebuf = &buf[0][0][0][0];                                         \
        if (wv == 0) {                                                          \
            float bv = (kh == 0) ? b2[cg*32 + (l & 31)] : 0.f;                  \
            float vals[3][16];                                                  \
            _Pragma("unroll")                                                   \
            for (int i = 0; i < 3; ++i)                                         \
                _Pragma("unroll")                                               \
                for (int r = 0; r < 16; ++r)                                    \
                    vals[i][r] = buf[0][i][r][l] + buf[1][i][r][l]              \
                               + buf[2][i][r][l] + buf[3][i][r][l] + bv;        \
            _Pragma("unroll")                                                   \
            for (int i = 0; i < 3; ++i)                                         \
                _Pragma("unroll")                                               \
                for (int r = 0; r < 16; ++r) {                                  \
                    int row = (r & 3) + 8*(r >> 2) + 4*(l >> 5);                \
                    ebuf[i*1056 + row*33 + (l & 31)] = vals[i][r];              \
                }                                                               \
        }                                                                       \
        __syncthreads();                                                        \
        _Pragma("unroll 1")                                                     \
        for (int pass = 0; pass < 6; ++pass) {                                  \
            int row_id = pass*16 + (t >> 5);                                    \
            int oxl = row_id >> 5, c = row_id & 31;                             \
            float v = ebuf[oxl*1056 + (t & 31)*33 + c];                         \
            int p = oy*6 + (POFF) + oxl;                                        \
            hp[(size_t)((cg*32 + c)*36 + p)*256 + bt*32 + (t & 31)] = v;        \
        }                                                                       \
        __syncthreads();                                                        \
    }
    REDUCE_STORE(0, 0)
    REDUCE_STORE(3, 3)
    #undef REDUCE_STORE
}

// -------- uhat: kh-partial sum + primary squash + u_hat + colpart (R20) -----
__global__ __launch_bounds__(256) void uhat_kernel(
        const float* __restrict__ h2t, const float* __restrict__ h2t2,
        const float* __restrict__ W, unsigned short* __restrict__ uhat,
        float* __restrict__ colpart) {
    int ch = blockIdx.x;      // 0..71 (16 n each)
    int c  = blockIdx.y;      // 0..9
    int t  = threadIdx.x;     // b
    __shared__ float Wl[2048];            // [16n][16i][8j]
    const float* wsrc = W + ((size_t)c*1152 + ch*16)*128;
    for (int i = t; i < 2048; i += 256) Wl[i] = wsrc[i];
    __syncthreads();
    float cp[16];
    #pragma unroll
    for (int i = 0; i < 16; ++i) cp[i] = 0.f;
    #pragma unroll 1
    for (int nn = 0; nn < 16; ++nn) {
        int n = ch*16 + nn;
        float v[8]; float sq = 0.f;
        #pragma unroll
        for (int j = 0; j < 8; ++j) {
            size_t idx = (size_t)(n*8 + j)*256 + t;
            v[j] = h2t[idx] + h2t2[idx];
            sq = fmaf(v[j], v[j], sq);
        }
        float sc = sq / (1.0f + sq);      // primary squash: NO /sqrt
        #pragma unroll
        for (int j = 0; j < 8; ++j) v[j] *= sc;
        #pragma unroll
        for (int i = 0; i < 16; ++i) {
            float uh = 0.f;
            #pragma unroll
            for (int j = 0; j < 8; ++j)
                uh = fmaf(Wl[(nn*16 + i)*8 + j], v[j], uh);
            unsigned short ub = bf16_rne(uh);
            uhat[((size_t)(c*16 + i)*1152 + n)*256 + t] = ub;
            cp[i] += bf16_tof(ub);        // chunk column-sum (bf16-rounded vals)
        }
    }
    #pragma unroll
    for (int i = 0; i < 16; ++i)
        colpart[(size_t)ch*40960 + (size_t)(c*16 + i)*256 + t] = cp[i];
}

// -------- rout: 3 routing iterations; 1024 thr (16 waves) per (c,i) ---------
__global__ __launch_bounds__(1024) void rout_kernel(
        const unsigned short* __restrict__ uhat, const float* __restrict__ colpart,
        float* __restrict__ ob) {
    int ci = blockIdx.x;      // 0..159
    int t  = threadIdx.x;     // 0..1023
    int wv = t >> 6, l = t & 63;
    const unsigned short* U = uhat + (size_t)ci*1152*256;
    __shared__ float bsum[1152];
    __shared__ float p[1152];
    __shared__ float outb[256];
    __shared__ float sred[32][256];       // 32 KB
    __shared__ float red[16];
    for (int k = t; k < 1152; k += 1024) bsum[k] = 0.f;
    __syncthreads();

    #define DELTA_PASS                                                          \
    {                                                                           \
        int nl = l >> 5, bo = l & 31;                                           \
        _Pragma("unroll 6")                                                     \
        for (int pass = 0; pass < 36; ++pass) {                                 \
            int n = pass*32 + wv*2 + nl;                                        \
            short8 u8 = *(const short8*)(U + (size_t)n*256 + bo*8);             \
            float d = 0.f;                                                      \
            _Pragma("unroll")                                                   \
            for (int e = 0; e < 8; ++e)                                         \
                d = fmaf(bf16_tof((unsigned short)u8[e]), outb[bo*8 + e], d);   \
            _Pragma("unroll")                                                   \
            for (int mm = 1; mm < 32; mm <<= 1) d += __shfl_xor(d, mm, 64);     \
            if (bo == 0) bsum[n] += d;                                          \
        }                                                                       \
    }

    // ---------------- iter 0: p uniform -> s from colpart ------------------
    {
        float s = 0.f;
        if (t < 256) {
            const float* cp = colpart + (size_t)ci*256 + t;
            #pragma unroll 8
            for (int ch = 0; ch < 72; ++ch) s += cp[(size_t)ch*40960];
            s *= (1.0f / 1152.0f);
        }
        float v2 = s * s;
        #pragma unroll
        for (int mm = 1; mm < 64; mm <<= 1) v2 += __shfl_xor(v2, mm, 64);
        if (t < 256 && l == 0) red[wv] = v2;   // waves 0..3
        __syncthreads();
        float total = red[0] + red[1] + red[2] + red[3];
        if (t < 256) {
            float scq = total / ((1.0f + total) * sqrtf(total));
            outb[t] = scq * s;
        }
        __syncthreads();
        DELTA_PASS
        __syncthreads();
    }

    // ---------------- iters 1,2 --------------------------------------------
    #pragma unroll 1
    for (int it = 1; it < 3; ++it) {
        // ---- softmax over n (1024 threads, 2 slices) ----
        float lv[2];
        float m = -1e30f;
        #pragma unroll
        for (int k = 0; k < 2; ++k) {
            int n = t + k*1024;
            lv[k] = (n < 1152) ? bsum[n] : -1e30f;
            m = fmaxf(m, lv[k]);
        }
        #pragma unroll
        for (int mm = 1; mm < 64; mm <<= 1) m = fmaxf(m, __shfl_xor(m, mm, 64));
        if (l == 0) red[wv] = m;
        __syncthreads();
        m = red[0];
        #pragma unroll
        for (int k = 1; k < 16; ++k) m = fmaxf(m, red[k]);
        __syncthreads();                   // WAR: red reused for sum
        float se = 0.f;
        #pragma unroll
        for (int k = 0; k < 2; ++k) {
            int n = t + k*1024;
            if (n < 1152) {
                float e = expf(lv[k] - m);
                p[n] = e;
                se += e;
            }
        }
        #pragma unroll
        for (int mm = 1; mm < 64; mm <<= 1) se += __shfl_xor(se, mm, 64);
        if (l == 0) red[wv] = se;
        __syncthreads();
        se = red[0];
        #pragma unroll
        for (int k = 1; k < 16; ++k) se += red[k];
        float inv = 1.0f / se;
        #pragma unroll
        for (int k = 0; k < 2; ++k) {
            int n = t + k*1024;
            if (n < 1152) p[n] *= inv;
        }
        __syncthreads();                   // p visible to all

        // ---- s-phase: thread (ng, bo) accumulates 8 b over its 36 n -------
        {
            int ng = t >> 5, bo = t & 31;
            float s8[8];
            #pragma unroll
            for (int e = 0; e < 8; ++e) s8[e] = 0.f;
            int n0 = ng * 36;
            #pragma unroll 6
            for (int nn = 0; nn < 36; ++nn) {
                int n = n0 + nn;
                float pv = p[n];
                short8 u8 = *(const short8*)(U + (size_t)n*256 + bo*8);
                #pragma unroll
                for (int e = 0; e < 8; ++e)
                    s8[e] = fmaf(pv, bf16_tof((unsigned short)u8[e]), s8[e]);
            }
            #pragma unroll
            for (int e = 0; e < 8; ++e) sred[ng][bo*8 + e] = s8[e];
        }
        __syncthreads();

        // ---- squash over b (threads 0..255) -------------------------------
        float s = 0.f;
        if (t < 256) {
            #pragma unroll
            for (int g = 0; g < 32; ++g) s += sred[g][t];
            float v2 = s * s;
            #pragma unroll
            for (int mm = 1; mm < 64; mm <<= 1) v2 += __shfl_xor(v2, mm, 64);
            if ((t & 63) == 0) red[t >> 6] = v2;
        }
        __syncthreads();
        float total = red[0] + red[1] + red[2] + red[3];
        if (t < 256) {
            float scq = total / ((1.0f + total) * sqrtf(total));
            float o = scq * s;
            if (it == 2) ob[(size_t)ci*256 + t] = o;
            else outb[t] = o;
        }
        if (it == 2) break;
        __syncthreads();                   // outb visible
        DELTA_PASS
        __syncthreads();
    }
    #undef DELTA_PASS
}

// -------- final: out[b,c] = sum_i outputs[c,i,b]^2 --------------------------
__global__ __launch_bounds__(256) void final_kernel(
        const float* __restrict__ obuf, float* __restrict__ out) {
    int c = blockIdx.x;
    int t = threadIdx.x;
    float s = 0.0f;
    #pragma unroll
    for (int i = 0; i < 16; ++i) {
        float v = obuf[((size_t)c*16 + i)*256 + t];
        s = fmaf(v, v, s);
    }
    out[(size_t)t*10 + c] = s;
}

// ---------------------------------------------------------------------------
extern "C" void kernel_launch(void* const* d_in, const int* in_sizes, int n_in,
                              void* d_out, int out_size, void* d_ws, size_t ws_size,
                              hipStream_t stream) {
    const float* x  = (const float*)d_in[0];
    const float* w1 = (const float*)d_in[1];
    const float* b1 = (const float*)d_in[2];
    const float* w2 = (const float*)d_in[3];
    const float* b2 = (const float*)d_in[4];
    const float* W  = (const float*)d_in[5];
    float* out = (float*)d_out;
    (void)in_sizes; (void)n_in; (void)out_size;

    if (ws_size < B_END_SPLIT) return;

    char* wsb = (char*)d_ws;
    unsigned short* qhi = (unsigned short*)(wsb + B_QHI);
    unsigned short* qlo = (unsigned short*)(wsb + B_QLO);
    unsigned short* whi = (unsigned short*)(wsb + B_WHI);
    unsigned short* wlo = (unsigned short*)(wsb + B_WLO);
    float* h2t  = (float*)(wsb + B_H2);
    float* h2t2 = (float*)(wsb + B_H2B);
    unsigned short* uh = (unsigned short*)(wsb + B_UH);   // aliases A2 (dead)
    float* ob = (float*)(wsb + B_OB);                     // aliases whi (dead)
    float* cp = (float*)(wsb + B_CP);                     // aliases whi/wlo (dead)

    prep_kernel<<<1024, 256, 0, stream>>>(x, w1, b1, w2, qhi, qlo, whi, wlo);
    conv2_mfma<<<768, 512, 0, stream>>>(qhi, qlo, whi, wlo, b2, h2t);
    uhat_kernel<<<dim3(72, 10), 256, 0, stream>>>(h2t, h2t2, W, uh, cp);
    rout_kernel<<<160, 1024, 0, stream>>>(uh, cp, ob);
    final_kernel<<<10, 256, 0, stream>>>(ob, out);
}